// Round 1
// 1165.294 us; speedup vs baseline: 1.0518x; 1.0518x over previous
//
#include <hip/hip_runtime.h>

#define NN 100000
#define LL 1024
#define HH 512
#define DD 256
#define TOPK 64
#define CAP 3072
#define CPB 4
#define DELTA 3e-3f

// ---- workspace layout (bytes) ----
#define WS_W1T   0u            // ushort[512*1024]
#define WS_B2    1048576u      // ushort[512*512]
#define WS_Z     1572864u      // zeroed region start
#define Z_MNUM   0u            // float[512]
#define Z_SEXP   2048u         // float
#define Z_LOSS   2052u         // float
#define Z_CNTT   2056u         // uint
#define Z_CNTB   2060u         // uint
#define Z_HIST   2064u         // uint[2048]
#define Z_WSA    10256u        // float[100032] (A accumulators, padded)
#define Z_PARAMS 410384u       // uint[8]: [0]=thrT [1]=thrB [2]=binT [3]=binB [4]=remT [5]=remB
#define Z_SEL    410416u       // uint[128]
#define Z_CANDT  410928u       // uint[3072]  (doubles as hist2T before k_collect)
#define Z_CANDB  423216u       // uint[3072]  (doubles as hist2B before k_collect)
#define Z_AEXT   435504u       // float[3072]
#define Z_AEXB   447792u       // float[3072]
#define Z_ZWORDS 108876        // words zeroed each launch (bytes [0, 435504) = through CANDB)

typedef float  f32x16 __attribute__((ext_vector_type(16)));
typedef short  bf16x8 __attribute__((ext_vector_type(8)));

#define MFMA(a,b,c) __builtin_amdgcn_mfma_f32_32x32x16_bf16(a,b,c,0,0,0)

__device__ __forceinline__ unsigned short f2bf(float x){
  unsigned u = __float_as_uint(x);
  u += 0x7FFFu + ((u >> 16) & 1u);          // round-to-nearest-even
  return (unsigned short)(u >> 16);
}
__device__ __forceinline__ float bf2f(unsigned short v){
  return __uint_as_float(((unsigned)v) << 16);
}
__device__ __forceinline__ unsigned sortable_u(float f){
  unsigned u = __float_as_uint(f);
  return (u & 0x80000000u) ? ~u : (u | 0x80000000u);
}
__device__ __forceinline__ float inv_sortable(unsigned u){
  unsigned orig = (u & 0x80000000u) ? (u ^ 0x80000000u) : ~u;
  return __uint_as_float(orig);
}
// packed f32->bf16 RNE (same rounding as f2bf)
__device__ __forceinline__ unsigned cvtpk(float lo, float hi){
  unsigned r;
  asm("v_cvt_pk_bf16_f32 %0, %1, %2" : "=v"(r) : "v"(lo), "v"(hi));
  return r;
}

// ---------------- K0: weight transpose/convert + zero scratch ----------------
// reads coalesced (row-major walk of W1/Wa/Wb), writes scattered (fire-and-forget)
__global__ void k0_prep(const float* __restrict__ W1, const float* __restrict__ Wa,
                        const float* __restrict__ Wb,
                        unsigned short* __restrict__ W1T, unsigned short* __restrict__ B2,
                        unsigned* __restrict__ zwords)
{
  const int n1 = HH * LL;        // 524288
  const int n2 = HH * HH;        // 262144
  const int tot = n1 + n2 + Z_ZWORDS;
  int stride = gridDim.x * 256;
  for (int idx = blockIdx.x * 256 + threadIdx.x; idx < tot; idx += stride){
    if (idx < n1){
      int k = idx >> 9, n = idx & 511;                 // idx = k*512+n -> coalesced W1 read
      W1T[(size_t)n * LL + k] = f2bf(W1[idx]);
    } else if (idx < n1 + n2){
      int j = idx - n1;
      int k = j >> 9, n = j & 511;
      int w = n >> 6, ii = n & 63;
      float v = (ii < 32) ? Wa[k * DD + (w * 32 + ii)] : Wb[k * DD + (w * 32 + ii - 32)];
      B2[(size_t)n * HH + k] = f2bf(v);
    } else {
      zwords[idx - n1 - n2] = 0u;
    }
  }
}

// ---------------- mega kernel: h1 GEMM + attention GEMM + A + M ----------------
__global__ __launch_bounds__(512, 2)
void k_mega(const float* __restrict__ h, const unsigned short* __restrict__ W1T,
            const unsigned short* __restrict__ B2g,
            const float* __restrict__ b1, const float* __restrict__ ba,
            const float* __restrict__ bbg, const float* __restrict__ Wc,
            const float* __restrict__ bc,
            float* __restrict__ outA,          // d_out + 5  (A_raw)
            float* __restrict__ wsA,           // zeroed accumulators (padded to 100032)
            float* __restrict__ Mnum, float* __restrict__ sum_exp)
{
  // 64 KB LDS: during GEMM1 first 10240 B = two bf16 A-tiles (stride 40, double
  // buffered); afterwards the whole buffer is the h1 block [64][512] bf16, swizzled.
  __shared__ __align__(16) unsigned short SM[64 * 512];

  const int tid  = threadIdx.x;
  const int wid  = tid >> 6;
  const int lane = tid & 63;
  const int l31  = lane & 31;
  const int half = lane >> 5;
  const int r0   = blockIdx.x * 64;

  // staging coords (fp32 h tile 64x32, 4 floats/thread)
  const int sr = tid >> 3;
  const int sc = (tid & 7) << 2;
  int gr = r0 + sr; if (gr > NN - 1) gr = NN - 1;
  const float* hp = h + (size_t)gr * LL + sc;

  const unsigned short* bp0 = W1T + (size_t)(wid * 64 + l31) * LL + half * 8;
  const unsigned short* bp1 = W1T + (size_t)(wid * 64 + 32 + l31) * LL + half * 8;

  f32x16 acc00 = (f32x16)0.f, acc01 = (f32x16)0.f, acc10 = (f32x16)0.f, acc11 = (f32x16)0.f;

  unsigned short* sbuf0 = SM;            // A-tile buffers, stride 40 shorts
  unsigned short* sbuf1 = SM + 2560;

  // ---- GEMM1 prologue: stage tile 0, prefetch tile 1 ----
  float4 av;
  {
    float4 a0 = *(const float4*)(hp);
    av = *(const float4*)(hp + 32);
    uint2 pk; pk.x = cvtpk(a0.x, a0.y); pk.y = cvtpk(a0.z, a0.w);
    *(uint2*)(sbuf0 + sr * 40 + sc) = pk;
  }
  asm volatile("s_waitcnt lgkmcnt(0)" ::: "memory");
  __builtin_amdgcn_s_barrier();
  __builtin_amdgcn_sched_barrier(0);

  unsigned short* rb = sbuf0;   // tile kc lives here
  unsigned short* wb = sbuf1;   // tile kc+1 staged here

  // One raw barrier per K-chunk; NO vmcnt drain anywhere in the loop.
  // Load order matters: B frags first, h prefetch after them, so the compiler's
  // counted vmcnt waits for B (at the MFMAs) never drain the h prefetch; the h
  // prefetch is only awaited at its conversion one full iteration later.
  #pragma unroll 1
  for (int kc = 0; kc < 32; ++kc){
    bf16x8 b00 = *(const bf16x8*)(bp0 + kc * 32);
    bf16x8 b10 = *(const bf16x8*)(bp1 + kc * 32);
    bf16x8 b01 = *(const bf16x8*)(bp0 + kc * 32 + 16);
    bf16x8 b11 = *(const bf16x8*)(bp1 + kc * 32 + 16);
    __builtin_amdgcn_sched_barrier(0);
    float4 cur = av;                                   // tile kc+1 data (in flight ~1 iter)
    av = *(const float4*)(hp + min(kc + 2, 31) * 32);  // prefetch tile kc+2
    __builtin_amdgcn_sched_barrier(0);
    // stage tile kc+1 -> wb (bf16, RNE)
    uint2 pk; pk.x = cvtpk(cur.x, cur.y); pk.y = cvtpk(cur.z, cur.w);
    *(uint2*)(wb + sr * 40 + sc) = pk;
    // compute tile kc from rb
    const unsigned short* a0p = rb + l31 * 40 + half * 8;
    const unsigned short* a1p = rb + (32 + l31) * 40 + half * 8;
    bf16x8 a0k0 = *(const bf16x8*)(a0p);
    bf16x8 a1k0 = *(const bf16x8*)(a1p);
    acc00 = MFMA(a0k0, b00, acc00); acc01 = MFMA(a0k0, b10, acc01);
    acc10 = MFMA(a1k0, b00, acc10); acc11 = MFMA(a1k0, b10, acc11);
    bf16x8 a0k1 = *(const bf16x8*)(a0p + 16);
    bf16x8 a1k1 = *(const bf16x8*)(a1p + 16);
    acc00 = MFMA(a0k1, b01, acc00); acc01 = MFMA(a0k1, b11, acc01);
    acc10 = MFMA(a1k1, b01, acc10); acc11 = MFMA(a1k1, b11, acc11);
    { unsigned short* t = rb; rb = wb; wb = t; }
    asm volatile("s_waitcnt lgkmcnt(0)" ::: "memory");  // my reads+write done; vmem stays in flight
    __builtin_amdgcn_sched_barrier(0);
    __builtin_amdgcn_s_barrier();
    __builtin_amdgcn_sched_barrier(0);
  }
  __syncthreads();   // all GEMM1 LDS traffic done; SM becomes h1 block

  // epilogue1: bias + relu + bf16, write swizzled h1 to LDS
  {
    float b1v0 = b1[wid * 64 + l31];
    float b1v1 = b1[wid * 64 + 32 + l31];
    int cb0 = wid * 8 + (l31 >> 3);        // chunk of col, nt=0
    int cb1 = wid * 8 + 4 + (l31 >> 3);    // nt=1
    int wi = l31 & 7;
    #pragma unroll
    for (int reg = 0; reg < 16; ++reg){
      int rA = (reg & 3) + ((reg >> 2) << 3) + (half << 2);
      int rB = rA + 32;
      float v;
      v = fmaxf(acc00[reg] + b1v0, 0.f); SM[rA * 512 + ((cb0 ^ (rA & 7)) << 3) + wi] = f2bf(v);
      v = fmaxf(acc01[reg] + b1v1, 0.f); SM[rA * 512 + ((cb1 ^ (rA & 7)) << 3) + wi] = f2bf(v);
      v = fmaxf(acc10[reg] + b1v0, 0.f); SM[rB * 512 + ((cb0 ^ (rB & 7)) << 3) + wi] = f2bf(v);
      v = fmaxf(acc11[reg] + b1v1, 0.f); SM[rB * 512 + ((cb1 ^ (rB & 7)) << 3) + wi] = f2bf(v);
    }
  }
  __syncthreads();

  // GEMM2: pre_a / pre_b = h1 @ [Wa|Wb] (interleaved B2); no barriers needed
  f32x16 q00 = (f32x16)0.f, q01 = (f32x16)0.f, q10 = (f32x16)0.f, q11 = (f32x16)0.f;
  const unsigned short* c0p = B2g + (size_t)(wid * 64 + l31) * HH + half * 8;
  const unsigned short* c1p = B2g + (size_t)(wid * 64 + 32 + l31) * HH + half * 8;
  const int m0x = l31 & 7;
  #pragma unroll 1
  for (int kc = 0; kc < 16; ++kc){
    #pragma unroll
    for (int ks = 0; ks < 2; ++ks){
      int ko = kc * 32 + ks * 16;
      int sw = (((kc * 4 + ks * 2 + half) ^ m0x) << 3);
      bf16x8 a0 = *(const bf16x8*)(SM + l31 * 512 + sw);
      bf16x8 a1 = *(const bf16x8*)(SM + (32 + l31) * 512 + sw);
      bf16x8 b0 = *(const bf16x8*)(c0p + ko);
      bf16x8 b1 = *(const bf16x8*)(c1p + ko);
      q00 = MFMA(a0, b0, q00); q01 = MFMA(a0, b1, q01);
      q10 = MFMA(a1, b0, q10); q11 = MFMA(a1, b1, q11);
    }
  }

  // epilogue2: A_row = sum_d tanh(pa)*sig(pb)*Wc[d]; reduce 32 cols then global atomics
  {
    int ca = wid * 32 + l31;
    float bav = ba[ca], bbv = bbg[ca], wcv = Wc[ca];
    #pragma unroll
    for (int mt = 0; mt < 2; ++mt){
      #pragma unroll
      for (int reg = 0; reg < 16; ++reg){
        float pav = (mt ? q10[reg] : q00[reg]) + bav;
        float pbv = (mt ? q11[reg] : q01[reg]) + bbv;
        float p = tanhf(pav) * (1.f / (1.f + expf(-pbv))) * wcv;
        p += __shfl_xor(p, 1, 64);  p += __shfl_xor(p, 2, 64);
        p += __shfl_xor(p, 4, 64);  p += __shfl_xor(p, 8, 64);
        p += __shfl_xor(p, 16, 64);
        if (l31 == 0){
          int rl = mt * 32 + (reg & 3) + ((reg >> 2) << 3) + (half << 2);
          atomicAdd(&wsA[r0 + rl], p);
        }
      }
    }
  }
  __syncthreads();                 // drains the atomics (vmcnt(0) before barrier)
  if (tid < 64){
    int g = r0 + tid;
    if (g < NN){
      float Ar = atomicAdd(&wsA[g], 0.0f) + bc[0];   // atomic read (L2)
      outA[g] = Ar;
    }
  }
  __syncthreads();

  // M partials: pm[col] = sum_r exp(A_r) * h1[r][col]
  float ev = 0.f;
  { int g = r0 + lane; if (g < NN) ev = expf(outA[g]); }
  float pm = 0.f;
  const int tch = tid >> 3, twi = tid & 7;
  #pragma unroll 4
  for (int r = 0; r < 64; ++r){
    float e = __shfl(ev, r, 64);
    pm += e * bf2f(SM[r * 512 + ((tch ^ (r & 7)) << 3) + twi]);
  }
  atomicAdd(&Mnum[tid], pm);
  if (wid == 0){
    float s = ev;
    s += __shfl_xor(s, 1, 64);  s += __shfl_xor(s, 2, 64);  s += __shfl_xor(s, 4, 64);
    s += __shfl_xor(s, 8, 64);  s += __shfl_xor(s, 16, 64); s += __shfl_xor(s, 32, 64);
    if (lane == 0) atomicAdd(sum_exp, s);
  }
}

// ---------------- selection pipeline ----------------
__global__ void k_hist(const float* __restrict__ A, unsigned* __restrict__ hist)
{
  __shared__ unsigned lh[2048];
  for (int i = threadIdx.x; i < 2048; i += 256) lh[i] = 0u;
  __syncthreads();
  for (int i = blockIdx.x * 256 + threadIdx.x; i < NN; i += gridDim.x * 256)
    atomicAdd(&lh[sortable_u(A[i]) >> 21], 1u);
  __syncthreads();
  for (int i = threadIdx.x; i < 2048; i += 256)
    if (lh[i]) atomicAdd(&hist[i], lh[i]);
}

// level-1 scan: find boundary bin + remaining count for each side
__global__ void k_scan(const unsigned* __restrict__ hist, unsigned* __restrict__ params)
{
  if (threadIdx.x == 0){
    unsigned c = 0, hh = 0; int b = 2047;
    for (; b >= 0; --b){ hh = hist[b]; c += hh; if (c >= TOPK) break; }
    if (b < 0) b = 0;
    params[2] = (unsigned)b;
    params[4] = TOPK - (c - hh);          // rem_top in [1,64]
    c = 0; hh = 0; int b2 = 0;
    for (; b2 < 2048; ++b2){ hh = hist[b2]; c += hh; if (c >= TOPK) break; }
    if (b2 > 2047) b2 = 2047;
    params[3] = (unsigned)b2;
    params[5] = TOPK - (c - hh);
  }
}

// level-2 histogram: 11 more sortable bits within each boundary bin
__global__ void k_hist2(const float* __restrict__ A, const unsigned* __restrict__ params,
                        unsigned* __restrict__ h2T, unsigned* __restrict__ h2B)
{
  __shared__ unsigned lh[4096];
  for (int i = threadIdx.x; i < 4096; i += 256) lh[i] = 0u;
  __syncthreads();
  unsigned bT = params[2], bB = params[3];
  for (int i = blockIdx.x * 256 + threadIdx.x; i < NN; i += gridDim.x * 256){
    unsigned u = sortable_u(A[i]);
    unsigned b = u >> 21;
    if (b == bT) atomicAdd(&lh[(u >> 10) & 2047u], 1u);
    if (b == bB) atomicAdd(&lh[2048 + ((u >> 10) & 2047u)], 1u);
  }
  __syncthreads();
  for (int i = threadIdx.x; i < 2048; i += 256){
    if (lh[i])        atomicAdd(&h2T[i], lh[i]);
    if (lh[2048 + i]) atomicAdd(&h2B[i], lh[2048 + i]);
  }
}

// level-2 scan: locate 64th value to ~2^-13 rel, apply value margin DELTA
__global__ __launch_bounds__(128)
void k_scan2(const unsigned* __restrict__ h2T, const unsigned* __restrict__ h2B,
             unsigned* __restrict__ params)
{
  int side = threadIdx.x >> 6;           // 0 = top, 1 = bottom (one wave each)
  int lane = threadIdx.x & 63;
  const unsigned* h2 = side ? h2B : h2T;
  unsigned bT  = params[2 + side];
  unsigned rem = params[4 + side];
  unsigned cs = 0;
  int base = lane * 32;
  #pragma unroll 4
  for (int j = 0; j < 32; ++j) cs += h2[base + j];
  unsigned before = 0;                   // count earlier in walk order
  for (int j = 0; j < 64; ++j){
    unsigned v = __shfl(cs, j, 64);
    bool earlier = side ? (j < lane) : (j > lane);
    if (earlier) before += v;
  }
  if (before < rem && before + cs >= rem){
    unsigned c = before; int s = base;
    if (side == 0){
      for (int b = base + 31; b >= base; --b){ c += h2[b]; if (c >= rem){ s = b; break; } }
      unsigned ulo = (bT << 21) | ((unsigned)s << 10);       // lower edge <= v64
      float v = inv_sortable(ulo) - DELTA;
      params[0] = sortable_u(v);
    } else {
      for (int b = base; b < base + 32; ++b){ c += h2[b]; if (c >= rem){ s = b; break; } }
      unsigned uhi = (bT << 21) | ((unsigned)s << 10) | 1023u; // upper edge >= v64
      float v = inv_sortable(uhi) + DELTA;
      params[1] = sortable_u(v);
    }
  }
}

__global__ void k_collect(const float* __restrict__ A, const unsigned* __restrict__ params,
                          unsigned* cntT, unsigned* cntB,
                          unsigned* __restrict__ candT, unsigned* __restrict__ candB)
{
  unsigned p0 = params[0], p1 = params[1];
  for (int i = blockIdx.x * 256 + threadIdx.x; i < NN; i += gridDim.x * 256){
    unsigned u = sortable_u(A[i]);
    if (u >= p0){ unsigned pos = atomicAdd(cntT, 1u); if (pos < CAP) candT[pos] = (unsigned)i; }
    if (u <= p1){ unsigned pos = atomicAdd(cntB, 1u); if (pos < CAP) candB[pos] = (unsigned)i; }
  }
}

__global__ __launch_bounds__(256)
void k_exact(const float* __restrict__ h, const float* __restrict__ W1, const float* __restrict__ b1,
             const float* __restrict__ Wa, const float* __restrict__ ba,
             const float* __restrict__ Wb, const float* __restrict__ bbg,
             const float* __restrict__ Wc, const float* __restrict__ bc,
             const unsigned* cntT, const unsigned* cntB,
             const unsigned* __restrict__ candT, const unsigned* __restrict__ candB,
             float* __restrict__ AexT, float* __restrict__ AexB)
{
  const int PB = CAP / CPB;
  int b = blockIdx.x;
  int side = (b >= PB) ? 1 : 0;
  int base = (side ? b - PB : b) * CPB;
  unsigned cnt = side ? *cntB : *cntT;
  if (cnt > CAP) cnt = CAP;
  if (base >= (int)cnt) return;
  int nc = min(CPB, (int)cnt - base);
  const unsigned* cand = side ? candB : candT;
  float* Aex = side ? AexB : AexT;

  __shared__ float hrow[CPB][LL];
  __shared__ float h1row[CPB][HH];
  __shared__ unsigned rows_s[CPB];
  __shared__ float red[4][CPB];
  int tid = threadIdx.x;
  if (tid < CPB) rows_s[tid] = cand[base + min(tid, nc - 1)];
  __syncthreads();
  for (int c = 0; c < CPB; ++c)
    ((float4*)hrow[c])[tid] = ((const float4*)(h + (size_t)rows_s[c] * LL))[tid];
  __syncthreads();

  float s0[CPB], s1[CPB];
  { float v0 = b1[tid], v1 = b1[tid + 256];
    #pragma unroll
    for (int c = 0; c < CPB; ++c){ s0[c] = v0; s1[c] = v1; } }
  for (int k = 0; k < LL; ++k){
    float w0 = W1[k * HH + tid];
    float w1 = W1[k * HH + tid + 256];
    #pragma unroll
    for (int c = 0; c < CPB; ++c){ float hv = hrow[c][k]; s0[c] += hv * w0; s1[c] += hv * w1; }
  }
  #pragma unroll
  for (int c = 0; c < CPB; ++c){
    h1row[c][tid] = fmaxf(s0[c], 0.f);
    h1row[c][tid + 256] = fmaxf(s1[c], 0.f);
  }
  __syncthreads();

  float pa[CPB], pb[CPB];
  float bav = ba[tid], bbv = bbg[tid], wcv = Wc[tid];
  #pragma unroll
  for (int c = 0; c < CPB; ++c){ pa[c] = bav; pb[c] = bbv; }
  for (int k = 0; k < HH; ++k){
    float wav = Wa[k * DD + tid];
    float wbv = Wb[k * DD + tid];
    #pragma unroll
    for (int c = 0; c < CPB; ++c){ float hv = h1row[c][k]; pa[c] += hv * wav; pb[c] += hv * wbv; }
  }
  int lane = tid & 63, w = tid >> 6;
  #pragma unroll
  for (int c = 0; c < CPB; ++c){
    float p = tanhf(pa[c]) * (1.f / (1.f + expf(-pb[c]))) * wcv;
    p += __shfl_xor(p, 1, 64);  p += __shfl_xor(p, 2, 64);  p += __shfl_xor(p, 4, 64);
    p += __shfl_xor(p, 8, 64);  p += __shfl_xor(p, 16, 64); p += __shfl_xor(p, 32, 64);
    if (lane == 0) red[w][c] = p;
  }
  __syncthreads();
  if (tid == 0)
    for (int c = 0; c < nc; ++c)
      Aex[base + c] = red[0][c] + red[1][c] + red[2][c] + red[3][c] + bc[0];
}

__global__ __launch_bounds__(256)
void k_select(const unsigned* cntT, const unsigned* cntB,
              const unsigned* __restrict__ candT, const unsigned* __restrict__ candB,
              const float* __restrict__ AexT, const float* __restrict__ AexB,
              unsigned* __restrict__ sel)
{
  __shared__ unsigned long long keys[CAP];
  __shared__ unsigned long long wmax[4];
  __shared__ unsigned long long best_s;
  int tid = threadIdx.x;
  for (int side = 0; side < 2; ++side){
    unsigned cnt = side ? *cntB : *cntT; if (cnt > CAP) cnt = CAP;
    const unsigned* cand = side ? candB : candT;
    const float* Aex = side ? AexB : AexT;
    for (int j = tid; j < (int)cnt; j += 256){
      unsigned su = sortable_u(Aex[j]);
      if (side) su = ~su;                                   // bottom: ascending A
      keys[j] = (((unsigned long long)su) << 32) | (unsigned long long)(0xFFFFFFFFu - cand[j]);
    }
    __syncthreads();
    for (int it = 0; it < TOPK; ++it){
      unsigned long long loc = 0ull;
      for (int j = tid; j < (int)cnt; j += 256){ unsigned long long k = keys[j]; loc = (k > loc) ? k : loc; }
      for (int off = 1; off < 64; off <<= 1){
        unsigned long long o = __shfl_xor(loc, off, 64);
        loc = (o > loc) ? o : loc;
      }
      if ((tid & 63) == 0) wmax[tid >> 6] = loc;
      __syncthreads();
      if (tid == 0){
        unsigned long long m01 = (wmax[0] > wmax[1]) ? wmax[0] : wmax[1];
        unsigned long long m23 = (wmax[2] > wmax[3]) ? wmax[2] : wmax[3];
        unsigned long long bb_ = (m01 > m23) ? m01 : m23;
        best_s = bb_;
        sel[side * TOPK + it] = 0xFFFFFFFFu - (unsigned)(bb_ & 0xFFFFFFFFull);
      }
      __syncthreads();
      unsigned long long bv = best_s;
      for (int j = tid; j < (int)cnt; j += 256) if (keys[j] == bv) keys[j] = 0ull;
      __syncthreads();
    }
    __syncthreads();
  }
}

// ---------------- instance path ----------------
__global__ __launch_bounds__(256)
void k_inst(const float* __restrict__ h, const float* __restrict__ W1, const float* __restrict__ b1,
            const float* __restrict__ Winst, const float* __restrict__ binst,
            const unsigned* __restrict__ sel, const int* __restrict__ labelp,
            float* __restrict__ out, float* __restrict__ loss_sum)
{
  __shared__ float hrow[LL];
  __shared__ float h1row[HH];
  __shared__ float red[4][2];
  int i = blockIdx.x, tid = threadIdx.x;
  unsigned row = sel[i];
  ((float4*)hrow)[tid] = ((const float4*)(h + (size_t)row * LL))[tid];
  __syncthreads();
  float s0 = b1[tid], s1 = b1[tid + 256];
  for (int k = 0; k < LL; ++k){
    float hv = hrow[k];
    s0 += hv * W1[k * HH + tid];
    s1 += hv * W1[k * HH + tid + 256];
  }
  h1row[tid] = fmaxf(s0, 0.f); h1row[tid + 256] = fmaxf(s1, 0.f);
  __syncthreads();
  float l0 = 0.f, l1 = 0.f;
  for (int d = tid; d < HH; d += 256){
    float hv = h1row[d];
    l0 += hv * Winst[d * 2];
    l1 += hv * Winst[d * 2 + 1];
  }
  for (int off = 1; off < 64; off <<= 1){ l0 += __shfl_xor(l0, off, 64); l1 += __shfl_xor(l1, off, 64); }
  if ((tid & 63) == 0){ red[tid >> 6][0] = l0; red[tid >> 6][1] = l1; }
  __syncthreads();
  if (tid == 0){
    float L0 = red[0][0] + red[1][0] + red[2][0] + red[3][0] + binst[0];
    float L1 = red[0][1] + red[1][1] + red[2][1] + red[3][1] + binst[1];
    int lab = labelp[0];
    int tgt = (i < TOPK) ? lab : 0;
    out[100006 + i] = (L1 > L0) ? 1.f : 0.f;     // all_preds (argmax, tie->0)
    out[100134 + i] = (float)tgt;                // all_targets
    float m = fmaxf(L0, L1);
    float lse = m + logf(expf(L0 - m) + expf(L1 - m));
    float lp = ((tgt == 1) ? L1 : L0) - lse;
    atomicAdd(loss_sum, -lp);
  }
}

// ---------------- bag head ----------------
__global__ __launch_bounds__(512)
void k_final(const float* __restrict__ Mnum, const float* __restrict__ sum_exp,
             const float* __restrict__ Wcls, const float* __restrict__ bcls,
             const float* __restrict__ loss_sum, float* __restrict__ out)
{
  __shared__ float red[8][2];
  int tid = threadIdx.x;
  float S = *sum_exp;
  float m = Mnum[tid] / S;
  float p0 = m * Wcls[tid * 2], p1 = m * Wcls[tid * 2 + 1];
  for (int off = 1; off < 64; off <<= 1){ p0 += __shfl_xor(p0, off, 64); p1 += __shfl_xor(p1, off, 64); }
  if ((tid & 63) == 0){ red[tid >> 6][0] = p0; red[tid >> 6][1] = p1; }
  __syncthreads();
  if (tid == 0){
    float L0 = bcls[0], L1 = bcls[1];
    for (int w = 0; w < 8; ++w){ L0 += red[w][0]; L1 += red[w][1]; }
    out[0] = L0; out[1] = L1;
    float mm = fmaxf(L0, L1);
    float e0 = expf(L0 - mm), e1 = expf(L1 - mm);
    out[2] = e0 / (e0 + e1); out[3] = e1 / (e0 + e1);
    out[4] = (L1 > L0) ? 1.f : 0.f;
    out[100005] = loss_sum[0] / 128.f;
  }
}

extern "C" void kernel_launch(void* const* d_in, const int* in_sizes, int n_in,
                              void* d_out, int out_size, void* d_ws, size_t ws_size,
                              hipStream_t stream)
{
  const float* h     = (const float*)d_in[0];
  const float* W1    = (const float*)d_in[1];
  const float* b1    = (const float*)d_in[2];
  const float* Wa    = (const float*)d_in[3];
  const float* ba    = (const float*)d_in[4];
  const float* Wb    = (const float*)d_in[5];
  const float* bbg   = (const float*)d_in[6];
  const float* Wc    = (const float*)d_in[7];
  const float* bc    = (const float*)d_in[8];
  const float* Winst = (const float*)d_in[9];
  const float* binst = (const float*)d_in[10];
  const float* Wcls  = (const float*)d_in[11];
  const float* bcls  = (const float*)d_in[12];
  const int*   label = (const int*)d_in[13];
  float* out = (float*)d_out;

  char* ws = (char*)d_ws;
  unsigned short* W1T = (unsigned short*)(ws + WS_W1T);
  unsigned short* B2  = (unsigned short*)(ws + WS_B2);
  char* Z = ws + WS_Z;
  float*    Mnum   = (float*)(Z + Z_MNUM);
  float*    sexp   = (float*)(Z + Z_SEXP);
  float*    lsum   = (float*)(Z + Z_LOSS);
  unsigned* cntT   = (unsigned*)(Z + Z_CNTT);
  unsigned* cntB   = (unsigned*)(Z + Z_CNTB);
  unsigned* hist   = (unsigned*)(Z + Z_HIST);
  float*    wsA    = (float*)(Z + Z_WSA);
  unsigned* params = (unsigned*)(Z + Z_PARAMS);
  unsigned* sel    = (unsigned*)(Z + Z_SEL);
  unsigned* candT  = (unsigned*)(Z + Z_CANDT);
  unsigned* candB  = (unsigned*)(Z + Z_CANDB);
  float*    AexT   = (float*)(Z + Z_AEXT);
  float*    AexB   = (float*)(Z + Z_AEXB);
  unsigned* h2T    = (unsigned*)(Z + Z_CANDT);   // aliases candT (consumed before k_collect)
  unsigned* h2B    = (unsigned*)(Z + Z_CANDB);   // aliases candB

  k0_prep<<<1024, 256, 0, stream>>>(W1, Wa, Wb, W1T, B2, (unsigned*)Z);
  k_mega<<<1563, 512, 0, stream>>>(h, W1T, B2, b1, ba, bbg, Wc, bc,
                                   out + 5, wsA, Mnum, sexp);
  k_hist<<<400, 256, 0, stream>>>(out + 5, hist);
  k_scan<<<1, 64, 0, stream>>>(hist, params);
  k_hist2<<<400, 256, 0, stream>>>(out + 5, params, h2T, h2B);
  k_scan2<<<1, 128, 0, stream>>>(h2T, h2B, params);
  k_collect<<<400, 256, 0, stream>>>(out + 5, params, cntT, cntB, candT, candB);
  k_exact<<<2 * (CAP / CPB), 256, 0, stream>>>(h, W1, b1, Wa, ba, Wb, bbg, Wc, bc,
                                               cntT, cntB, candT, candB, AexT, AexB);
  k_select<<<1, 256, 0, stream>>>(cntT, cntB, candT, candB, AexT, AexB, sel);
  k_inst<<<128, 256, 0, stream>>>(h, W1, b1, Winst, binst, sel, label, out, lsum);
  k_final<<<1, 512, 0, stream>>>(Mnum, sexp, Wcls, bcls, lsum, out);
}

// Round 2
// 1100.721 us; speedup vs baseline: 1.1135x; 1.0587x over previous
//
#include <hip/hip_runtime.h>

#define NN 100000
#define LL 1024
#define HH 512
#define DD 256
#define TOPK 64
#define CAP 3072
#define CPB 4
#define DELTA 3e-3f

// ---- workspace layout (bytes) ----
#define WS_W1T   0u            // ushort[512*1024]  (fragment-major W1F)
#define WS_B2    1048576u      // ushort[512*512]   (fragment-major B2F)
#define WS_Z     1572864u      // zeroed region start
#define Z_MNUM   0u            // float[512]
#define Z_SEXP   2048u         // float
#define Z_LOSS   2052u         // float
#define Z_CNTT   2056u         // uint
#define Z_CNTB   2060u         // uint
#define Z_HIST   2064u         // uint[2048]
#define Z_WSA    10256u        // float[100032] (A accumulators, padded)
#define Z_PARAMS 410384u       // uint[8]: [0]=thrT [1]=thrB [2]=binT [3]=binB [4]=remT [5]=remB
#define Z_SEL    410416u       // uint[128]
#define Z_CANDT  410928u       // uint[3072]  (doubles as hist2T before k_collect)
#define Z_CANDB  423216u       // uint[3072]  (doubles as hist2B before k_collect)
#define Z_AEXT   435504u       // float[3072]
#define Z_AEXB   447792u       // float[3072]
#define Z_ZWORDS 108876        // words zeroed each launch (bytes [0, 435504))

typedef float  f32x16 __attribute__((ext_vector_type(16)));
typedef short  bf16x8 __attribute__((ext_vector_type(8)));

#define MFMA(a,b,c) __builtin_amdgcn_mfma_f32_32x32x16_bf16(a,b,c,0,0,0)

__device__ __forceinline__ unsigned short f2bf(float x){
  unsigned u = __float_as_uint(x);
  u += 0x7FFFu + ((u >> 16) & 1u);          // round-to-nearest-even
  return (unsigned short)(u >> 16);
}
__device__ __forceinline__ float bf2f(unsigned short v){
  return __uint_as_float(((unsigned)v) << 16);
}
__device__ __forceinline__ unsigned sortable_u(float f){
  unsigned u = __float_as_uint(f);
  return (u & 0x80000000u) ? ~u : (u | 0x80000000u);
}
__device__ __forceinline__ float inv_sortable(unsigned u){
  unsigned orig = (u & 0x80000000u) ? (u ^ 0x80000000u) : ~u;
  return __uint_as_float(orig);
}
// packed f32->bf16 RNE (same rounding as f2bf)
__device__ __forceinline__ unsigned cvtpk(float lo, float hi){
  unsigned r;
  asm("v_cvt_pk_bf16_f32 %0, %1, %2" : "=v"(r) : "v"(lo), "v"(hi));
  return r;
}

// ---------------- K0: weight repack to MFMA-fragment-major + zero scratch ----
// Fragment layout (32x32x16 bf16 MFMA, B operand):
//   W1F frag(c,s), c=n>>5 (16), s=k>>4 (64): lane ln=(l31,half) holds
//   W1[k=16s+8*half+j][n=32c+l31], j=0..7 -> 16B. Flat short offset:
//   ((c*64+s)*64+ln)*8.  B2F same with s<32, n interleaved [Wa|Wb] by 32-col
//   groups. All global reads and writes coalesced; transpose via LDS tile.
__global__ __launch_bounds__(256)
void k0_prep(const float* __restrict__ W1, const float* __restrict__ Wa,
             const float* __restrict__ Wb,
             unsigned short* __restrict__ W1F, unsigned short* __restrict__ B2F,
             unsigned* __restrict__ zwords)
{
  __shared__ unsigned short T[16 * 512];
  int b = blockIdx.x, tid = threadIdx.x;
  if (b < 64){
    int s = b;                      // k-slice of 16 rows of W1
    #pragma unroll
    for (int i = 0; i < 8; ++i){
      int g = tid + 256 * i;        // float4 index among 16*128
      int kk = g >> 7, c4 = g & 127;
      float4 v = *(const float4*)(W1 + (size_t)(16 * s + kk) * HH + c4 * 4);
      uint2 pk; pk.x = cvtpk(v.x, v.y); pk.y = cvtpk(v.z, v.w);
      *(uint2*)(T + kk * 512 + c4 * 4) = pk;
    }
    __syncthreads();
    int c = tid >> 4, lbase = (tid & 15) * 4;
    #pragma unroll
    for (int q = 0; q < 4; ++q){
      int l = lbase + q; int l31 = l & 31; int kh = l >> 5;
      unsigned short tmp[8];
      #pragma unroll
      for (int j = 0; j < 8; ++j) tmp[j] = T[(kh * 8 + j) * 512 + c * 32 + l31];
      *(bf16x8*)(W1F + ((size_t)(c * 64 + s) * 64 + l) * 8) = *(bf16x8*)tmp;
    }
  } else if (b < 96){
    int s = b - 64;                 // k-slice of 16 rows of Wa/Wb
    #pragma unroll
    for (int i = 0; i < 4; ++i){
      int g = tid + 256 * i;        // float4 index among 16*64
      int kk = g >> 6, c4 = g & 63;
      float4 va = *(const float4*)(Wa + (size_t)(16 * s + kk) * DD + c4 * 4);
      float4 vb = *(const float4*)(Wb + (size_t)(16 * s + kk) * DD + c4 * 4);
      uint2 pa; pa.x = cvtpk(va.x, va.y); pa.y = cvtpk(va.z, va.w);
      uint2 pb; pb.x = cvtpk(vb.x, vb.y); pb.y = cvtpk(vb.z, vb.w);
      *(uint2*)(T + kk * 512 + c4 * 4) = pa;
      *(uint2*)(T + kk * 512 + 256 + c4 * 4) = pb;
    }
    __syncthreads();
    int c = tid >> 4, lbase = (tid & 15) * 4;
    int col0 = (c & 1) * 256 + (c >> 1) * 32;   // [Wa(0..255)|Wb(256..511)]
    #pragma unroll
    for (int q = 0; q < 4; ++q){
      int l = lbase + q; int l31 = l & 31; int kh = l >> 5;
      unsigned short tmp[8];
      #pragma unroll
      for (int j = 0; j < 8; ++j) tmp[j] = T[(kh * 8 + j) * 512 + col0 + l31];
      *(bf16x8*)(B2F + ((size_t)(c * 32 + s) * 64 + l) * 8) = *(bf16x8*)tmp;
    }
  } else {
    for (int i = (b - 96) * 256 + tid; i < Z_ZWORDS; i += 32 * 256) zwords[i] = 0u;
  }
}

// ---------------- mega kernel: h1 GEMM + attention GEMM + A + M ----------------
// GEMM1: h staged in 4 K-chunks of 256 (2x32KB LDS double buffer). Every global
// load (h rows and B fragments) is a single contiguous 1KB wave burst.
__global__ __launch_bounds__(512, 2)
void k_mega(const float* __restrict__ h, const unsigned short* __restrict__ W1F,
            const unsigned short* __restrict__ B2F,
            const float* __restrict__ b1, const float* __restrict__ ba,
            const float* __restrict__ bbg, const float* __restrict__ Wc,
            const float* __restrict__ bc,
            float* __restrict__ outA,          // d_out + 5  (A_raw)
            float* __restrict__ wsA,           // zeroed accumulators (padded to 100032)
            float* __restrict__ Mnum, float* __restrict__ sum_exp)
{
  // 64 KB LDS: during GEMM1 two 32KB chunk buffers [64][256] bf16 (XOR-swizzled
  // 16B chunks); afterwards the whole buffer is the h1 block [64][512] bf16.
  __shared__ __align__(16) unsigned short SM[64 * 512];

  const int tid  = threadIdx.x;
  const int wid  = tid >> 6;
  const int lane = tid & 63;
  const int l31  = lane & 31;
  const int half = lane >> 5;
  const int r0   = blockIdx.x * 64;

  // staging coords: thread owns float4-column scol of rows srow+8j (full-row
  // wave bursts: lanes of a wave cover one contiguous 1KB row segment)
  const int scol = tid & 63;
  const int srow = tid >> 6;

  // B fragment base: frag(c,s) short offset = c*32768 + s*512 + lane*8
  const unsigned short* bp = W1F + (size_t)(2 * wid) * 32768 + (size_t)lane * 8;

  f32x16 acc00 = (f32x16)0.f, acc01 = (f32x16)0.f, acc10 = (f32x16)0.f, acc11 = (f32x16)0.f;

  unsigned short* buf0 = SM;
  unsigned short* buf1 = SM + 64 * 256;

  // A-chunk LDS addressing: row r stride 256 shorts; 16B chunk idx (0..31)
  // XOR-swizzled with (r&31); write 8B halves.
  // ---- prologue: stage chunk 0 ----
  #pragma unroll
  for (int j = 0; j < 8; ++j){
    int r = srow + 8 * j;
    int gr = r0 + r; if (gr > NN - 1) gr = NN - 1;
    float4 v = *(const float4*)(h + (size_t)gr * LL + scol * 4);
    uint2 pk; pk.x = cvtpk(v.x, v.y); pk.y = cvtpk(v.z, v.w);
    *(uint2*)(buf0 + r * 256 + ((((scol >> 1) ^ (r & 31)) << 3) + (scol & 1) * 4)) = pk;
  }
  __syncthreads();

  unsigned short* rb = buf0;
  unsigned short* wb = buf1;

#define SUBIT(i) { \
    const int s0_ = sb + 2 * (i), s1_ = s0_ + 1; \
    bf16x8 b00 = *(const bf16x8*)(bp + s0_ * 512); \
    bf16x8 b01 = *(const bf16x8*)(bp + s1_ * 512); \
    bf16x8 b10 = *(const bf16x8*)(bp + 32768 + s0_ * 512); \
    bf16x8 b11 = *(const bf16x8*)(bp + 32768 + s1_ * 512); \
    const int ck0 = 4 * (i) + half, ck1 = ck0 + 2; \
    bf16x8 a0k0 = *(const bf16x8*)(rb + l31 * 256 + ((ck0 ^ l31) << 3)); \
    bf16x8 a1k0 = *(const bf16x8*)(rb + (32 + l31) * 256 + ((ck0 ^ l31) << 3)); \
    bf16x8 a0k1 = *(const bf16x8*)(rb + l31 * 256 + ((ck1 ^ l31) << 3)); \
    bf16x8 a1k1 = *(const bf16x8*)(rb + (32 + l31) * 256 + ((ck1 ^ l31) << 3)); \
    acc00 = MFMA(a0k0, b00, acc00); acc01 = MFMA(a0k0, b10, acc01); \
    acc10 = MFMA(a1k0, b00, acc10); acc11 = MFMA(a1k0, b10, acc11); \
    acc00 = MFMA(a0k1, b01, acc00); acc01 = MFMA(a0k1, b11, acc01); \
    acc10 = MFMA(a1k1, b01, acc10); acc11 = MFMA(a1k1, b11, acc11); }

#define LDH(dst, j) { \
    int r_ = srow + 8 * (j); \
    int gr_ = r0 + r_; if (gr_ > NN - 1) gr_ = NN - 1; \
    dst = *(const float4*)(h + (size_t)gr_ * LL + coff + scol * 4); }

#define WRH(v, j) { \
    int r_ = srow + 8 * (j); \
    uint2 pk_; pk_.x = cvtpk((v).x, (v).y); pk_.y = cvtpk((v).z, (v).w); \
    *(uint2*)(wb + r_ * 256 + ((((scol >> 1) ^ (r_ & 31)) << 3) + (scol & 1) * 4)) = pk_; }

  #pragma unroll 1
  for (int ch = 0; ch < 4; ++ch){
    const int sb = ch * 16;
    const int coff = (ch + 1) * 256;     // next chunk's float column base
    const bool st = (ch < 3);
    float4 hA, hB;
    if (st){ LDH(hA, 0) LDH(hB, 1) }
    SUBIT(0) SUBIT(1)
    if (st){ WRH(hA, 0) WRH(hB, 1) LDH(hA, 2) LDH(hB, 3) }
    SUBIT(2) SUBIT(3)
    if (st){ WRH(hA, 2) WRH(hB, 3) LDH(hA, 4) LDH(hB, 5) }
    SUBIT(4) SUBIT(5)
    if (st){ WRH(hA, 4) WRH(hB, 5) LDH(hA, 6) LDH(hB, 7) }
    SUBIT(6) SUBIT(7)
    if (st){ WRH(hA, 6) WRH(hB, 7) }
    __syncthreads();
    { unsigned short* t = rb; rb = wb; wb = t; }
  }

  // epilogue1: bias + relu + bf16, write swizzled h1 [64][512] to LDS
  {
    float b1v0 = b1[wid * 64 + l31];
    float b1v1 = b1[wid * 64 + 32 + l31];
    int cb0 = wid * 8 + (l31 >> 3);        // chunk of col, nt=0
    int cb1 = wid * 8 + 4 + (l31 >> 3);    // nt=1
    int wi = l31 & 7;
    #pragma unroll
    for (int reg = 0; reg < 16; ++reg){
      int rA = (reg & 3) + ((reg >> 2) << 3) + (half << 2);
      int rB = rA + 32;
      float v;
      v = fmaxf(acc00[reg] + b1v0, 0.f); SM[rA * 512 + ((cb0 ^ (rA & 7)) << 3) + wi] = f2bf(v);
      v = fmaxf(acc01[reg] + b1v1, 0.f); SM[rA * 512 + ((cb1 ^ (rA & 7)) << 3) + wi] = f2bf(v);
      v = fmaxf(acc10[reg] + b1v0, 0.f); SM[rB * 512 + ((cb0 ^ (rB & 7)) << 3) + wi] = f2bf(v);
      v = fmaxf(acc11[reg] + b1v1, 0.f); SM[rB * 512 + ((cb1 ^ (rB & 7)) << 3) + wi] = f2bf(v);
    }
  }
  __syncthreads();

  // GEMM2: pre_a / pre_b = h1 @ [Wa|Wb] (fragment-major B2F); no barriers needed
  f32x16 q00 = (f32x16)0.f, q01 = (f32x16)0.f, q10 = (f32x16)0.f, q11 = (f32x16)0.f;
  const unsigned short* p2 = B2F + (size_t)(2 * wid) * 16384 + (size_t)lane * 8;
  const int m0x = l31 & 7;
  #pragma unroll 1
  for (int kc = 0; kc < 16; ++kc){
    #pragma unroll
    for (int ks = 0; ks < 2; ++ks){
      int s = kc * 2 + ks;
      bf16x8 b0 = *(const bf16x8*)(p2 + s * 512);
      bf16x8 b1 = *(const bf16x8*)(p2 + 16384 + s * 512);
      int sw = (((kc * 4 + ks * 2 + half) ^ m0x) << 3);
      bf16x8 a0 = *(const bf16x8*)(SM + l31 * 512 + sw);
      bf16x8 a1 = *(const bf16x8*)(SM + (32 + l31) * 512 + sw);
      q00 = MFMA(a0, b0, q00); q01 = MFMA(a0, b1, q01);
      q10 = MFMA(a1, b0, q10); q11 = MFMA(a1, b1, q11);
    }
  }

  // epilogue2: A_row = sum_d tanh(pa)*sig(pb)*Wc[d]; reduce 32 cols then global atomics
  {
    int ca = wid * 32 + l31;
    float bav = ba[ca], bbv = bbg[ca], wcv = Wc[ca];
    #pragma unroll
    for (int mt = 0; mt < 2; ++mt){
      #pragma unroll
      for (int reg = 0; reg < 16; ++reg){
        float pav = (mt ? q10[reg] : q00[reg]) + bav;
        float pbv = (mt ? q11[reg] : q01[reg]) + bbv;
        float p = tanhf(pav) * (1.f / (1.f + expf(-pbv))) * wcv;
        p += __shfl_xor(p, 1, 64);  p += __shfl_xor(p, 2, 64);
        p += __shfl_xor(p, 4, 64);  p += __shfl_xor(p, 8, 64);
        p += __shfl_xor(p, 16, 64);
        if (l31 == 0){
          int rl = mt * 32 + (reg & 3) + ((reg >> 2) << 3) + (half << 2);
          atomicAdd(&wsA[r0 + rl], p);
        }
      }
    }
  }
  __syncthreads();                 // drains the atomics (vmcnt(0) before barrier)
  if (tid < 64){
    int g = r0 + tid;
    if (g < NN){
      float Ar = atomicAdd(&wsA[g], 0.0f) + bc[0];   // atomic read (L2)
      outA[g] = Ar;
    }
  }
  __syncthreads();

  // M partials: pm[col] = sum_r exp(A_r) * h1[r][col]
  float ev = 0.f;
  { int g = r0 + lane; if (g < NN) ev = expf(outA[g]); }
  float pm = 0.f;
  const int tch = tid >> 3, twi = tid & 7;
  #pragma unroll 4
  for (int r = 0; r < 64; ++r){
    float e = __shfl(ev, r, 64);
    pm += e * bf2f(SM[r * 512 + ((tch ^ (r & 7)) << 3) + twi]);
  }
  atomicAdd(&Mnum[tid], pm);
  if (wid == 0){
    float s = ev;
    s += __shfl_xor(s, 1, 64);  s += __shfl_xor(s, 2, 64);  s += __shfl_xor(s, 4, 64);
    s += __shfl_xor(s, 8, 64);  s += __shfl_xor(s, 16, 64); s += __shfl_xor(s, 32, 64);
    if (lane == 0) atomicAdd(sum_exp, s);
  }
}

// ---------------- selection pipeline ----------------
__global__ void k_hist(const float* __restrict__ A, unsigned* __restrict__ hist)
{
  __shared__ unsigned lh[2048];
  for (int i = threadIdx.x; i < 2048; i += 256) lh[i] = 0u;
  __syncthreads();
  for (int i = blockIdx.x * 256 + threadIdx.x; i < NN; i += gridDim.x * 256)
    atomicAdd(&lh[sortable_u(A[i]) >> 21], 1u);
  __syncthreads();
  for (int i = threadIdx.x; i < 2048; i += 256)
    if (lh[i]) atomicAdd(&hist[i], lh[i]);
}

// level-1 scan: find boundary bin + remaining count for each side
__global__ void k_scan(const unsigned* __restrict__ hist, unsigned* __restrict__ params)
{
  if (threadIdx.x == 0){
    unsigned c = 0, hh = 0; int b = 2047;
    for (; b >= 0; --b){ hh = hist[b]; c += hh; if (c >= TOPK) break; }
    if (b < 0) b = 0;
    params[2] = (unsigned)b;
    params[4] = TOPK - (c - hh);          // rem_top in [1,64]
    c = 0; hh = 0; int b2 = 0;
    for (; b2 < 2048; ++b2){ hh = hist[b2]; c += hh; if (c >= TOPK) break; }
    if (b2 > 2047) b2 = 2047;
    params[3] = (unsigned)b2;
    params[5] = TOPK - (c - hh);
  }
}

// level-2 histogram: 11 more sortable bits within each boundary bin
__global__ void k_hist2(const float* __restrict__ A, const unsigned* __restrict__ params,
                        unsigned* __restrict__ h2T, unsigned* __restrict__ h2B)
{
  __shared__ unsigned lh[4096];
  for (int i = threadIdx.x; i < 4096; i += 256) lh[i] = 0u;
  __syncthreads();
  unsigned bT = params[2], bB = params[3];
  for (int i = blockIdx.x * 256 + threadIdx.x; i < NN; i += gridDim.x * 256){
    unsigned u = sortable_u(A[i]);
    unsigned b = u >> 21;
    if (b == bT) atomicAdd(&lh[(u >> 10) & 2047u], 1u);
    if (b == bB) atomicAdd(&lh[2048 + ((u >> 10) & 2047u)], 1u);
  }
  __syncthreads();
  for (int i = threadIdx.x; i < 2048; i += 256){
    if (lh[i])        atomicAdd(&h2T[i], lh[i]);
    if (lh[2048 + i]) atomicAdd(&h2B[i], lh[2048 + i]);
  }
}

// level-2 scan: locate 64th value to ~2^-13 rel, apply value margin DELTA
__global__ __launch_bounds__(128)
void k_scan2(const unsigned* __restrict__ h2T, const unsigned* __restrict__ h2B,
             unsigned* __restrict__ params)
{
  int side = threadIdx.x >> 6;           // 0 = top, 1 = bottom (one wave each)
  int lane = threadIdx.x & 63;
  const unsigned* h2 = side ? h2B : h2T;
  unsigned bT  = params[2 + side];
  unsigned rem = params[4 + side];
  unsigned cs = 0;
  int base = lane * 32;
  #pragma unroll 4
  for (int j = 0; j < 32; ++j) cs += h2[base + j];
  unsigned before = 0;                   // count earlier in walk order
  for (int j = 0; j < 64; ++j){
    unsigned v = __shfl(cs, j, 64);
    bool earlier = side ? (j < lane) : (j > lane);
    if (earlier) before += v;
  }
  if (before < rem && before + cs >= rem){
    unsigned c = before; int s = base;
    if (side == 0){
      for (int b = base + 31; b >= base; --b){ c += h2[b]; if (c >= rem){ s = b; break; } }
      unsigned ulo = (bT << 21) | ((unsigned)s << 10);       // lower edge <= v64
      float v = inv_sortable(ulo) - DELTA;
      params[0] = sortable_u(v);
    } else {
      for (int b = base; b < base + 32; ++b){ c += h2[b]; if (c >= rem){ s = b; break; } }
      unsigned uhi = (bT << 21) | ((unsigned)s << 10) | 1023u; // upper edge >= v64
      float v = inv_sortable(uhi) + DELTA;
      params[1] = sortable_u(v);
    }
  }
}

__global__ void k_collect(const float* __restrict__ A, const unsigned* __restrict__ params,
                          unsigned* cntT, unsigned* cntB,
                          unsigned* __restrict__ candT, unsigned* __restrict__ candB)
{
  unsigned p0 = params[0], p1 = params[1];
  for (int i = blockIdx.x * 256 + threadIdx.x; i < NN; i += gridDim.x * 256){
    unsigned u = sortable_u(A[i]);
    if (u >= p0){ unsigned pos = atomicAdd(cntT, 1u); if (pos < CAP) candT[pos] = (unsigned)i; }
    if (u <= p1){ unsigned pos = atomicAdd(cntB, 1u); if (pos < CAP) candB[pos] = (unsigned)i; }
  }
}

__global__ __launch_bounds__(256)
void k_exact(const float* __restrict__ h, const float* __restrict__ W1, const float* __restrict__ b1,
             const float* __restrict__ Wa, const float* __restrict__ ba,
             const float* __restrict__ Wb, const float* __restrict__ bbg,
             const float* __restrict__ Wc, const float* __restrict__ bc,
             const unsigned* cntT, const unsigned* cntB,
             const unsigned* __restrict__ candT, const unsigned* __restrict__ candB,
             float* __restrict__ AexT, float* __restrict__ AexB)
{
  const int PB = CAP / CPB;
  int b = blockIdx.x;
  int side = (b >= PB) ? 1 : 0;
  int base = (side ? b - PB : b) * CPB;
  unsigned cnt = side ? *cntB : *cntT;
  if (cnt > CAP) cnt = CAP;
  if (base >= (int)cnt) return;
  int nc = min(CPB, (int)cnt - base);
  const unsigned* cand = side ? candB : candT;
  float* Aex = side ? AexB : AexT;

  __shared__ float hrow[CPB][LL];
  __shared__ float h1row[CPB][HH];
  __shared__ unsigned rows_s[CPB];
  __shared__ float red[4][CPB];
  int tid = threadIdx.x;
  if (tid < CPB) rows_s[tid] = cand[base + min(tid, nc - 1)];
  __syncthreads();
  for (int c = 0; c < CPB; ++c)
    ((float4*)hrow[c])[tid] = ((const float4*)(h + (size_t)rows_s[c] * LL))[tid];
  __syncthreads();

  float s0[CPB], s1[CPB];
  { float v0 = b1[tid], v1 = b1[tid + 256];
    #pragma unroll
    for (int c = 0; c < CPB; ++c){ s0[c] = v0; s1[c] = v1; } }
  for (int k = 0; k < LL; ++k){
    float w0 = W1[k * HH + tid];
    float w1 = W1[k * HH + tid + 256];
    #pragma unroll
    for (int c = 0; c < CPB; ++c){ float hv = hrow[c][k]; s0[c] += hv * w0; s1[c] += hv * w1; }
  }
  #pragma unroll
  for (int c = 0; c < CPB; ++c){
    h1row[c][tid] = fmaxf(s0[c], 0.f);
    h1row[c][tid + 256] = fmaxf(s1[c], 0.f);
  }
  __syncthreads();

  float pa[CPB], pb[CPB];
  float bav = ba[tid], bbv = bbg[tid], wcv = Wc[tid];
  #pragma unroll
  for (int c = 0; c < CPB; ++c){ pa[c] = bav; pb[c] = bbv; }
  for (int k = 0; k < HH; ++k){
    float wav = Wa[k * DD + tid];
    float wbv = Wb[k * DD + tid];
    #pragma unroll
    for (int c = 0; c < CPB; ++c){ float hv = h1row[c][k]; pa[c] += hv * wav; pb[c] += hv * wbv; }
  }
  int lane = tid & 63, w = tid >> 6;
  #pragma unroll
  for (int c = 0; c < CPB; ++c){
    float p = tanhf(pa[c]) * (1.f / (1.f + expf(-pb[c]))) * wcv;
    p += __shfl_xor(p, 1, 64);  p += __shfl_xor(p, 2, 64);  p += __shfl_xor(p, 4, 64);
    p += __shfl_xor(p, 8, 64);  p += __shfl_xor(p, 16, 64); p += __shfl_xor(p, 32, 64);
    if (lane == 0) red[w][c] = p;
  }
  __syncthreads();
  if (tid == 0)
    for (int c = 0; c < nc; ++c)
      Aex[base + c] = red[0][c] + red[1][c] + red[2][c] + red[3][c] + bc[0];
}

__global__ __launch_bounds__(256)
void k_select(const unsigned* cntT, const unsigned* cntB,
              const unsigned* __restrict__ candT, const unsigned* __restrict__ candB,
              const float* __restrict__ AexT, const float* __restrict__ AexB,
              unsigned* __restrict__ sel)
{
  __shared__ unsigned long long keys[CAP];
  __shared__ unsigned long long wmax[4];
  __shared__ unsigned long long best_s;
  int tid = threadIdx.x;
  for (int side = 0; side < 2; ++side){
    unsigned cnt = side ? *cntB : *cntT; if (cnt > CAP) cnt = CAP;
    const unsigned* cand = side ? candB : candT;
    const float* Aex = side ? AexB : AexT;
    for (int j = tid; j < (int)cnt; j += 256){
      unsigned su = sortable_u(Aex[j]);
      if (side) su = ~su;                                   // bottom: ascending A
      keys[j] = (((unsigned long long)su) << 32) | (unsigned long long)(0xFFFFFFFFu - cand[j]);
    }
    __syncthreads();
    for (int it = 0; it < TOPK; ++it){
      unsigned long long loc = 0ull;
      for (int j = tid; j < (int)cnt; j += 256){ unsigned long long k = keys[j]; loc = (k > loc) ? k : loc; }
      for (int off = 1; off < 64; off <<= 1){
        unsigned long long o = __shfl_xor(loc, off, 64);
        loc = (o > loc) ? o : loc;
      }
      if ((tid & 63) == 0) wmax[tid >> 6] = loc;
      __syncthreads();
      if (tid == 0){
        unsigned long long m01 = (wmax[0] > wmax[1]) ? wmax[0] : wmax[1];
        unsigned long long m23 = (wmax[2] > wmax[3]) ? wmax[2] : wmax[3];
        unsigned long long bb_ = (m01 > m23) ? m01 : m23;
        best_s = bb_;
        sel[side * TOPK + it] = 0xFFFFFFFFu - (unsigned)(bb_ & 0xFFFFFFFFull);
      }
      __syncthreads();
      unsigned long long bv = best_s;
      for (int j = tid; j < (int)cnt; j += 256) if (keys[j] == bv) keys[j] = 0ull;
      __syncthreads();
    }
    __syncthreads();
  }
}

// ---------------- instance path ----------------
__global__ __launch_bounds__(256)
void k_inst(const float* __restrict__ h, const float* __restrict__ W1, const float* __restrict__ b1,
            const float* __restrict__ Winst, const float* __restrict__ binst,
            const unsigned* __restrict__ sel, const int* __restrict__ labelp,
            float* __restrict__ out, float* __restrict__ loss_sum)
{
  __shared__ float hrow[LL];
  __shared__ float h1row[HH];
  __shared__ float red[4][2];
  int i = blockIdx.x, tid = threadIdx.x;
  unsigned row = sel[i];
  ((float4*)hrow)[tid] = ((const float4*)(h + (size_t)row * LL))[tid];
  __syncthreads();
  float s0 = b1[tid], s1 = b1[tid + 256];
  for (int k = 0; k < LL; ++k){
    float hv = hrow[k];
    s0 += hv * W1[k * HH + tid];
    s1 += hv * W1[k * HH + tid + 256];
  }
  h1row[tid] = fmaxf(s0, 0.f); h1row[tid + 256] = fmaxf(s1, 0.f);
  __syncthreads();
  float l0 = 0.f, l1 = 0.f;
  for (int d = tid; d < HH; d += 256){
    float hv = h1row[d];
    l0 += hv * Winst[d * 2];
    l1 += hv * Winst[d * 2 + 1];
  }
  for (int off = 1; off < 64; off <<= 1){ l0 += __shfl_xor(l0, off, 64); l1 += __shfl_xor(l1, off, 64); }
  if ((tid & 63) == 0){ red[tid >> 6][0] = l0; red[tid >> 6][1] = l1; }
  __syncthreads();
  if (tid == 0){
    float L0 = red[0][0] + red[1][0] + red[2][0] + red[3][0] + binst[0];
    float L1 = red[0][1] + red[1][1] + red[2][1] + red[3][1] + binst[1];
    int lab = labelp[0];
    int tgt = (i < TOPK) ? lab : 0;
    out[100006 + i] = (L1 > L0) ? 1.f : 0.f;     // all_preds (argmax, tie->0)
    out[100134 + i] = (float)tgt;                // all_targets
    float m = fmaxf(L0, L1);
    float lse = m + logf(expf(L0 - m) + expf(L1 - m));
    float lp = ((tgt == 1) ? L1 : L0) - lse;
    atomicAdd(loss_sum, -lp);
  }
}

// ---------------- bag head ----------------
__global__ __launch_bounds__(512)
void k_final(const float* __restrict__ Mnum, const float* __restrict__ sum_exp,
             const float* __restrict__ Wcls, const float* __restrict__ bcls,
             const float* __restrict__ loss_sum, float* __restrict__ out)
{
  __shared__ float red[8][2];
  int tid = threadIdx.x;
  float S = *sum_exp;
  float m = Mnum[tid] / S;
  float p0 = m * Wcls[tid * 2], p1 = m * Wcls[tid * 2 + 1];
  for (int off = 1; off < 64; off <<= 1){ p0 += __shfl_xor(p0, off, 64); p1 += __shfl_xor(p1, off, 64); }
  if ((tid & 63) == 0){ red[tid >> 6][0] = p0; red[tid >> 6][1] = p1; }
  __syncthreads();
  if (tid == 0){
    float L0 = bcls[0], L1 = bcls[1];
    for (int w = 0; w < 8; ++w){ L0 += red[w][0]; L1 += red[w][1]; }
    out[0] = L0; out[1] = L1;
    float mm = fmaxf(L0, L1);
    float e0 = expf(L0 - mm), e1 = expf(L1 - mm);
    out[2] = e0 / (e0 + e1); out[3] = e1 / (e0 + e1);
    out[4] = (L1 > L0) ? 1.f : 0.f;
    out[100005] = loss_sum[0] / 128.f;
  }
}

extern "C" void kernel_launch(void* const* d_in, const int* in_sizes, int n_in,
                              void* d_out, int out_size, void* d_ws, size_t ws_size,
                              hipStream_t stream)
{
  const float* h     = (const float*)d_in[0];
  const float* W1    = (const float*)d_in[1];
  const float* b1    = (const float*)d_in[2];
  const float* Wa    = (const float*)d_in[3];
  const float* ba    = (const float*)d_in[4];
  const float* Wb    = (const float*)d_in[5];
  const float* bbg   = (const float*)d_in[6];
  const float* Wc    = (const float*)d_in[7];
  const float* bc    = (const float*)d_in[8];
  const float* Winst = (const float*)d_in[9];
  const float* binst = (const float*)d_in[10];
  const float* Wcls  = (const float*)d_in[11];
  const float* bcls  = (const float*)d_in[12];
  const int*   label = (const int*)d_in[13];
  float* out = (float*)d_out;

  char* ws = (char*)d_ws;
  unsigned short* W1F = (unsigned short*)(ws + WS_W1T);
  unsigned short* B2F = (unsigned short*)(ws + WS_B2);
  char* Z = ws + WS_Z;
  float*    Mnum   = (float*)(Z + Z_MNUM);
  float*    sexp   = (float*)(Z + Z_SEXP);
  float*    lsum   = (float*)(Z + Z_LOSS);
  unsigned* cntT   = (unsigned*)(Z + Z_CNTT);
  unsigned* cntB   = (unsigned*)(Z + Z_CNTB);
  unsigned* hist   = (unsigned*)(Z + Z_HIST);
  float*    wsA    = (float*)(Z + Z_WSA);
  unsigned* params = (unsigned*)(Z + Z_PARAMS);
  unsigned* sel    = (unsigned*)(Z + Z_SEL);
  unsigned* candT  = (unsigned*)(Z + Z_CANDT);
  unsigned* candB  = (unsigned*)(Z + Z_CANDB);
  float*    AexT   = (float*)(Z + Z_AEXT);
  float*    AexB   = (float*)(Z + Z_AEXB);
  unsigned* h2T    = (unsigned*)(Z + Z_CANDT);   // aliases candT (consumed before k_collect)
  unsigned* h2B    = (unsigned*)(Z + Z_CANDB);   // aliases candB

  k0_prep<<<128, 256, 0, stream>>>(W1, Wa, Wb, W1F, B2F, (unsigned*)Z);
  k_mega<<<1563, 512, 0, stream>>>(h, W1F, B2F, b1, ba, bbg, Wc, bc,
                                   out + 5, wsA, Mnum, sexp);
  k_hist<<<400, 256, 0, stream>>>(out + 5, hist);
  k_scan<<<1, 64, 0, stream>>>(hist, params);
  k_hist2<<<400, 256, 0, stream>>>(out + 5, params, h2T, h2B);
  k_scan2<<<1, 128, 0, stream>>>(h2T, h2B, params);
  k_collect<<<400, 256, 0, stream>>>(out + 5, params, cntT, cntB, candT, candB);
  k_exact<<<2 * (CAP / CPB), 256, 0, stream>>>(h, W1, b1, Wa, ba, Wb, bbg, Wc, bc,
                                               cntT, cntB, candT, candB, AexT, AexB);
  k_select<<<1, 256, 0, stream>>>(cntT, cntB, candT, candB, AexT, AexB, sel);
  k_inst<<<128, 256, 0, stream>>>(h, W1, b1, Winst, binst, sel, label, out, lsum);
  k_final<<<1, 512, 0, stream>>>(Mnum, sexp, Wcls, bcls, lsum, out);
}